// Round 20
// baseline (557.112 us; speedup 1.0000x reference)
//
#include <hip/hip_runtime.h>
#include <hip/hip_bf16.h>

typedef __bf16 bf16x8_t __attribute__((ext_vector_type(8)));
typedef __bf16 bf16x4_t __attribute__((ext_vector_type(4)));
typedef short s16x4_t  __attribute__((ext_vector_type(4)));
typedef float f32x4_t  __attribute__((ext_vector_type(4)));

#define NB 2
#define NS 2048
#define NHID 3584
#define NHEADS 16
#define NKVH 8
#define DH 256
#define WIN 1024

__device__ __forceinline__ float bf2f(ushort u) {
  union { unsigned v; float f; } x; x.v = ((unsigned)u) << 16; return x.f;
}
__device__ __forceinline__ ushort f2bf(float f) {
  unsigned x = __builtin_bit_cast(unsigned, f);
  unsigned r = (x + 0x7fffu + ((x >> 16) & 1u)) >> 16;
  return (ushort)r;
}

__device__ __forceinline__ void gload16(const void* g, void* l) {
  __builtin_amdgcn_global_load_lds((const __attribute__((address_space(1))) void*)g,
                                   (__attribute__((address_space(3))) void*)l, 16, 0, 0);
}

__device__ __forceinline__ f32x4_t mfma_pv(s16x4_t a, s16x4_t b, f32x4_t c) {
#if __has_builtin(__builtin_amdgcn_mfma_f32_16x16x16_bf16)
  return __builtin_amdgcn_mfma_f32_16x16x16_bf16(
      __builtin_bit_cast(bf16x4_t, a), __builtin_bit_cast(bf16x4_t, b), c, 0, 0, 0);
#else
  return __builtin_amdgcn_mfma_f32_16x16x16bf16_1k(a, b, c, 0, 0, 0);
#endif
}

__device__ __forceinline__ float fexp2(float x) {
#if __has_builtin(__builtin_amdgcn_exp2f)
  return __builtin_amdgcn_exp2f(x);
#else
  return exp2f(x);
#endif
}
__device__ __forceinline__ float frcp(float x) {
#if __has_builtin(__builtin_amdgcn_rcpf)
  return __builtin_amdgcn_rcpf(x);
#else
  return 1.0f / x;
#endif
}

// softcap softmax weight, uniformly scaled by e^-25 (cancels in l-normalize):
// p' = exp(25 - 100/(e^{2x}+1)), x = s/800  ==> exp2 form, clamp-free
__device__ __forceinline__ float pexp(float s) {
  float e = fexp2(s * 0.0036067376f);
  float r = frcp(e + 1.0f);
  return fexp2(36.067376f - 144.2695041f * r);
}

// ---------------- f32 -> bf16 elementwise convert (x4 vectorized) ---------
__global__ __launch_bounds__(256) void f32_to_bf16_kernel(const float* __restrict__ in,
                                                          ushort* __restrict__ out, int n4) {
  int i = (int)blockIdx.x * 256 + (int)threadIdx.x;
  if (i < n4) {
    float4 v = ((const float4*)in)[i];
    ushort4 o;
    o.x = f2bf(v.x); o.y = f2bf(v.y); o.z = f2bf(v.z); o.w = f2bf(v.w);
    ((ushort4*)out)[i] = o;
  }
}

// ------------- transpose+convert: f32 in[R][C] -> bf16 out[C][R] ----------
__global__ __launch_bounds__(256) void transpose_f32_bf16(const float* __restrict__ in,
                                                          ushort* __restrict__ out,
                                                          int R, int Cc) {
  __shared__ ushort tile[64][72];
  const int t = threadIdx.x;
  const int ct = Cc >> 6;
  const int by = blockIdx.x / ct;
  const int bx = blockIdx.x % ct;
  const int r0 = by << 6, c0 = bx << 6;
#pragma unroll
  for (int i = 0; i < 4; ++i) {
    int v = i * 256 + t;
    int r = v >> 4, c4 = (v & 15) << 2;
    float4 f = *(const float4*)(in + (size_t)(r0 + r) * Cc + c0 + c4);
    ushort4 o;
    o.x = f2bf(f.x); o.y = f2bf(f.y); o.z = f2bf(f.z); o.w = f2bf(f.w);
    *(ushort4*)&tile[r][c4] = o;
  }
  __syncthreads();
#pragma unroll
  for (int i = 0; i < 2; ++i) {
    int v = i * 256 + t;
    int rr = v >> 3;
    int c8 = (v & 7) << 3;
    ushort o[8];
#pragma unroll
    for (int e = 0; e < 8; ++e) o[e] = tile[c8 + e][rr];
    *(uint4*)(out + (size_t)(c0 + rr) * R + r0 + c8) = *(const uint4*)o;
  }
}

// ============ 256x256 GEMM, BK=32, 4-deep circular buffer, counted vmcnt ==
// T3+T4 faithful: stage tile t+3 while computing t; boundary waits vmcnt(8)
// (FIFO retire => oldest 4 loads = tile t+1 landed; t+2/t+3 stay in flight).
// Never drains to 0 in the main loop (m218). LDS: A bufs 4x16KB @0, B bufs
// 4x16KB @64K. Rows 64B, chunk XOR (row&3): ds_read_b128 = uniform 2-way
// (free); gload16 linear dest + inverse-swizzled source (rule 21).
// EPI=1: bf16 C + fused RoPE. EPI=2: f32 C. EPI=5: fused KV (K rope'd ->
// kbuf; V -> vtbuf ATTN-TILED: plane*524288 + (s>>5)*8192 + (d>>4)*512 +
// ((s&31)>>2)*64 + (d&15)*4 + (s&3)).
template <int EPI>
__global__ __launch_bounds__(512, 2) void gemm256(const ushort* __restrict__ A,
                                                  const ushort* __restrict__ Bt,
                                                  void* __restrict__ Cout,
                                                  const float* __restrict__ sinT,
                                                  const float* __restrict__ cosT,
                                                  int M, int N, int K) {
  __shared__ alignas(16) char lds[131072];
  const int t = threadIdx.x;
  const int lane = t & 63;
  const int wid = t >> 6;
  const int wm = wid >> 2;   // 0..1
  const int wn = wid & 3;    // 0..3
  const int g = lane >> 4;
  const int lr = lane & 15;

  const int nbn = N >> 8;
  const int nwg = (int)gridDim.x;
  const int bid = (int)blockIdx.x;
  const int swz = (bid & 7) * (nwg >> 3) + (bid >> 3);
  const int bm = swz / nbn, bn = swz % nbn;
  const int m0 = bm << 8, n0 = bn << 8;

  f32x4_t acc[8][4] = {};
  const int T = K >> 5;  // BK = 32

  auto stageAB = [&](int tt) {
    const int bufo = (tt & 3) << 14;
    const int koff = tt << 5;
#pragma unroll
    for (int j = 0; j < 2; ++j) {
      int idx = (j << 9) + t;                 // 0..1023
      int row = idx >> 2;
      int sc = (idx & 3) ^ (row & 3);         // inverse-swizzled source chunk
      gload16(A + (size_t)(m0 + row) * K + koff + (sc << 3),
              lds + bufo + (idx << 4));
      gload16(Bt + (size_t)(n0 + row) * K + koff + (sc << 3),
              lds + 65536 + bufo + (idx << 4));
    }
  };
  auto ldAfrag = [&](bf16x8_t* dst, int tt, int mh) {
    const char* cA = lds + ((tt & 3) << 14);
#pragma unroll
    for (int i = 0; i < 4; ++i) {
      int row = (wm << 7) + (mh << 6) + (i << 4) + lr;
      dst[i] = *(const bf16x8_t*)(cA + (row << 6) + ((g << 4) ^ ((row & 3) << 4)));
    }
  };
  auto ldBfrag = [&](bf16x8_t* dst, int tt) {
    const char* cB = lds + 65536 + ((tt & 3) << 14);
#pragma unroll
    for (int j = 0; j < 4; ++j) {
      int row = (wn << 6) + (j << 4) + lr;
      dst[j] = *(const bf16x8_t*)(cB + (row << 6) + ((g << 4) ^ ((row & 3) << 4)));
    }
  };

  // prologue: stage tiles 0,1,2 (12 loads/thread); wait oldest 4 (tile 0)
  stageAB(0); stageAB(1); stageAB(2);
  asm volatile("s_waitcnt vmcnt(8)" ::: "memory");
  __builtin_amdgcn_sched_barrier(0);
  __builtin_amdgcn_s_barrier();

  bf16x8_t afA[4], afB[4], bfv[4];
  ldAfrag(afA, 0, 0);
  ldBfrag(bfv, 0);

  for (int tt = 0; tt < T; ++tt) {
    if (tt + 3 < T) stageAB(tt + 3);        // into buf (tt+3)&3 = (tt-1)&3: safe
    ldAfrag(afB, tt, 1);                    // mh1 frags (counted lgkm before ph1)
    __builtin_amdgcn_s_setprio(1);
#pragma unroll
    for (int i = 0; i < 4; ++i)
#pragma unroll
      for (int j = 0; j < 4; ++j)
        acc[i][j] = __builtin_amdgcn_mfma_f32_16x16x32_bf16(afA[i], bfv[j], acc[i][j], 0, 0, 0);
    __builtin_amdgcn_s_setprio(0);
    __builtin_amdgcn_s_setprio(1);
#pragma unroll
    for (int i = 0; i < 4; ++i)
#pragma unroll
      for (int j = 0; j < 4; ++j)
        acc[4 + i][j] = __builtin_amdgcn_mfma_f32_16x16x32_bf16(afB[i], bfv[j], acc[4 + i][j], 0, 0, 0);
    __builtin_amdgcn_s_setprio(0);
    __builtin_amdgcn_s_barrier();           // all waves done reading buf tt
    if (tt + 1 < T) {
      if (tt + 3 < T)      asm volatile("s_waitcnt vmcnt(8)" ::: "memory");
      else if (tt + 2 < T) asm volatile("s_waitcnt vmcnt(4)" ::: "memory");
      else                 asm volatile("s_waitcnt vmcnt(0)" ::: "memory");
      __builtin_amdgcn_sched_barrier(0);
      ldAfrag(afA, tt + 1, 0);
      ldBfrag(bfv, tt + 1);
    }
  }

  // ---- epilogue: stage tile in LDS, then wide (rope-fused) stores ----
  __syncthreads();
  const bool trstage = (EPI == 5) && (n0 >= 2048);
  if (trstage) {
#pragma unroll
    for (int i = 0; i < 8; ++i)
#pragma unroll
      for (int j = 0; j < 4; ++j) {
        int col = (wn << 6) + (j << 4) + lr;
#pragma unroll
        for (int r = 0; r < 4; ++r) {
          int row = (wm << 7) + (i << 4) + (g << 2) + r;
          *(ushort*)(lds + (col << 9) + ((row << 1) ^ ((col & 7) << 4))) = f2bf(acc[i][j][r]);
        }
      }
  } else {
#pragma unroll
    for (int i = 0; i < 8; ++i)
#pragma unroll
      for (int j = 0; j < 4; ++j) {
        int col = (wn << 6) + (j << 4) + lr;
#pragma unroll
        for (int r = 0; r < 4; ++r) {
          int row = (wm << 7) + (i << 4) + (g << 2) + r;
          *(ushort*)(lds + (row << 9) + ((col << 1) ^ ((row & 7) << 4))) = f2bf(acc[i][j][r]);
        }
      }
  }
  __syncthreads();

  if (EPI == 1) {
    ushort* C = (ushort*)Cout;
#pragma unroll
    for (int it = 0; it < 16; ++it) {
      int idx = it * 512 + t;
      int row = idx >> 5, ch = idx & 31;
      uint4 v = *(const uint4*)(lds + (row << 9) + ((ch << 4) ^ ((row & 7) << 4)));
      uint4 p = *(const uint4*)(lds + (row << 9) + (((ch ^ 16) << 4) ^ ((row & 7) << 4)));
      int pos = (m0 + row) & (NS - 1);
      int d0 = ch << 3;
      float4 c0 = *(const float4*)(cosT + (size_t)pos * 256 + d0);
      float4 c1 = *(const float4*)(cosT + (size_t)pos * 256 + d0 + 4);
      float4 s0 = *(const float4*)(sinT + (size_t)pos * 256 + d0);
      float4 s1 = *(const float4*)(sinT + (size_t)pos * 256 + d0 + 4);
      float cs[8] = {c0.x, c0.y, c0.z, c0.w, c1.x, c1.y, c1.z, c1.w};
      float ss[8] = {s0.x, s0.y, s0.z, s0.w, s1.x, s1.y, s1.z, s1.w};
      const float sgn = (ch < 16) ? -1.f : 1.f;
      const ushort* vv = (const ushort*)&v;
      const ushort* pp = (const ushort*)&p;
      ushort o[8];
#pragma unroll
      for (int e = 0; e < 8; ++e)
        o[e] = f2bf(bf2f(vv[e]) * cs[e] + sgn * bf2f(pp[e]) * ss[e]);
      *(uint4*)(C + (size_t)(m0 + row) * N + n0 + (ch << 3)) = *(const uint4*)o;
    }
  } else if (EPI == 5) {
    ushort* C = (ushort*)Cout;
    if (n0 < 2048) {  // K half -> kbuf, WITH RoPE
#pragma unroll
      for (int it = 0; it < 16; ++it) {
        int idx = it * 512 + t;
        int row = idx >> 5, ch = idx & 31;
        uint4 v = *(const uint4*)(lds + (row << 9) + ((ch << 4) ^ ((row & 7) << 4)));
        uint4 p = *(const uint4*)(lds + (row << 9) + (((ch ^ 16) << 4) ^ ((row & 7) << 4)));
        int pos = (m0 + row) & (NS - 1);
        int d0 = ch << 3;
        float4 c0 = *(const float4*)(cosT + (size_t)pos * 256 + d0);
        float4 c1 = *(const float4*)(cosT + (size_t)pos * 256 + d0 + 4);
        float4 s0 = *(const float4*)(sinT + (size_t)pos * 256 + d0);
        float4 s1 = *(const float4*)(sinT + (size_t)pos * 256 + d0 + 4);
        float cs[8] = {c0.x, c0.y, c0.z, c0.w, c1.x, c1.y, c1.z, c1.w};
        float ss[8] = {s0.x, s0.y, s0.z, s0.w, s1.x, s1.y, s1.z, s1.w};
        const float sgn = (ch < 16) ? -1.f : 1.f;
        const ushort* vv = (const ushort*)&v;
        const ushort* pp = (const ushort*)&p;
        ushort o[8];
#pragma unroll
        for (int e = 0; e < 8; ++e)
          o[e] = f2bf(bf2f(vv[e]) * cs[e] + sgn * bf2f(pp[e]) * ss[e]);
        *(uint4*)(C + (size_t)(m0 + row) * 2048 + n0 + (ch << 3)) = *(const uint4*)o;
      }
    } else {
      // V half -> tiled vtbuf (no rope). Fully linear store: elem = base + s*8.
      ushort* vC = C + (size_t)4096 * 2048;
      const int plane = (m0 >> 11) * NKVH + ((n0 - 2048) >> 8);
      ushort* dst = vC + (size_t)plane * ((size_t)NS * DH) + (size_t)((m0 & (NS - 1)) >> 5) * 8192;
#pragma unroll
      for (int it = 0; it < 16; ++it) {
        int s = it * 512 + t;
        int lr2 = s & 7, kq = (s >> 3) & 7, dt_l = (s >> 6) & 15, sb_l = s >> 10;
        int d0 = (dt_l << 4) + (lr2 << 1);   // lds col
        int r0 = (sb_l << 5) + (kq << 2);    // lds row (token)
        uint2 a = *(const uint2*)(lds + (d0 << 9) + ((r0 << 1) ^ ((d0 & 7) << 4)));
        uint2 b2 = *(const uint2*)(lds + ((d0 + 1) << 9) + ((r0 << 1) ^ (((d0 + 1) & 7) << 4)));
        uint4 v; v.x = a.x; v.y = a.y; v.z = b2.x; v.w = b2.y;
        *(uint4*)(dst + (size_t)s * 8) = v;
      }
    }
  } else {
    float* Cf = (float*)Cout;
#pragma unroll
    for (int it = 0; it < 32; ++it) {
      int idx = it * 512 + t;
      int row = idx >> 6, qd = idx & 63;
      ushort4 hv = *(const ushort4*)(lds + (row << 9) + ((qd << 3) ^ ((row & 7) << 4)));
      float4 fv;
      fv.x = bf2f(hv.x); fv.y = bf2f(hv.y); fv.z = bf2f(hv.z); fv.w = bf2f(hv.w);
      *(float4*)(Cf + (size_t)(m0 + row) * N + n0 + (qd << 2)) = fv;
    }
  }
}

// ---------------- flash attention v6.1 (best measured: 147us) --------------
// grid 1024. xcd=bid&7 -> planes {2x,2x+1}; heavy q-blocks first (LPT).
// Tiled-V (linear gload16, bank-bijective PV reads). exp2 softcap softmax.
__global__ __launch_bounds__(256) void attn_kernel(const ushort* __restrict__ q,
                                                   const ushort* __restrict__ k,
                                                   const ushort* __restrict__ vt,
                                                   ushort* __restrict__ ao) {
  __shared__ alignas(16) char lK[2][16384];
  __shared__ alignas(16) char lV[2][16384];
  const int bid = (int)blockIdx.x;
  const int x = bid & 7;
  const int s_ = bid >> 3;       // 0..127
  const int rnd = s_ >> 5;       // 0..3
  const int c = s_ & 31;
  const int a = c >> 1;
  const int hl = c & 1;
  const int plane = (x << 1) | (rnd & 1);
  int qb;
  if (rnd < 2) qb = 16 + a;          // heavy first (LPT)
  else if (rnd == 2) qb = a;         // light ascending
  else qb = 15 - a;                  // light descending
  const int b = plane >> 3;
  const int kvh = plane & 7;
  const int h = (kvh << 1) | hl;
  const int qb0 = qb << 6;
  const int t = threadIdx.x;
  const int lane = t & 63;
  const int w = t >> 6;
  const int g = lane >> 4;
  const int lr = lane & 15;

  const int qrow = qb0 + (w << 4) + lr;
  bf16x8_t qf[8];
  const ushort* qbase = q + (size_t)(b * NS + qrow) * (NHEADS * DH) + h * DH;
#pragma unroll
  for (int ks = 0; ks < 8; ++ks)
    qf[ks] = *(const bf16x8_t*)(qbase + (ks << 5) + (g << 3));

  float l_r = 0.f;
  f32x4_t oacc[16] = {};

  const int qminw = qb0 + (w << 4);
  const int qmaxw = qminw + 15;
  int t_lo = qb0 - (WIN - 1);
  if (t_lo < 0) t_lo = 0;
  t_lo &= ~31;
  const int t_hi = qb0 + 63;
  const int nt = ((t_hi - t_lo) >> 5) + 1;

  const ushort* kgb = k + (size_t)(b * NS) * (NKVH * DH) + kvh * DH;
  const ushort* vgb = vt + (size_t)(b * NKVH + kvh) * ((size_t)NS * DH);  // tiled plane

  auto stage = [&](int kt, int bi) {
    char* dk = lK[bi];
    char* dv = lV[bi];
    const int sb = kt >> 5;
#pragma unroll
    for (int j = 0; j < 4; ++j) {
      int i = (w << 2) + j;  // 0..15
      int row = (i << 1) + (lane >> 5);
      int ck = (lane & 31) ^ (row & 7);
      gload16(kgb + (size_t)(kt + row) * (NKVH * DH) + (ck << 3), dk + (i << 10));
      gload16(vgb + (size_t)sb * 8192 + (((i << 6) + lane) << 3), dv + (i << 10));
    }
  };

  int cur = 0;
  stage(t_lo, 0);
  __syncthreads();

  for (int i = 0; i < nt; ++i) {
    const int kt = t_lo + (i << 5);
    if (i + 1 < nt) stage(kt + 32, cur ^ 1);  // async prefetch into other buf
    const char* lk = lK[cur];
    const char* lv = lV[cur];
#pragma unroll
    for (int sub = 0; sub < 2; ++sub) {
      const int key0 = kt + (sub << 4);
      if (key0 > qmaxw) continue;
      if (key0 + 15 < qminw - (WIN - 1)) continue;

      f32x4_t sacc = {};
      __builtin_amdgcn_s_setprio(1);
#pragma unroll
      for (int ks = 0; ks < 8; ++ks) {
        int row = (sub << 4) + lr;
        bf16x8_t kf = *(const bf16x8_t*)(lk + (((row << 9) + (ks << 6) + (g << 4)) ^ ((row & 7) << 4)));
        sacc = __builtin_amdgcn_mfma_f32_16x16x32_bf16(kf, qf[ks], sacc, 0, 0, 0);
      }
      __builtin_amdgcn_s_setprio(0);

      float pvv[4];
      const bool full = (key0 + 15 <= qminw) && (key0 >= qmaxw - (WIN - 1));
      if (full) {
#pragma unroll
        for (int r = 0; r < 4; ++r) { pvv[r] = pexp(sacc[r]); l_r += pvv[r]; }
      } else {
#pragma unroll
        for (int r = 0; r < 4; ++r) {
          int key = key0 + (g << 2) + r;
          bool ok = (key <= qrow) && (qrow - key < WIN);
          pvv[r] = ok ? pexp(sacc[r]) : 0.f;
          l_r += pvv[r];
        }
      }

      s16x4_t pa;  // truncating f32->bf16 (bias <=0.4%, inside threshold)
      pa[0] = (short)(ushort)(__builtin_bit_cast(unsigned, pvv[0]) >> 16);
      pa[1] = (short)(ushort)(__builtin_bit_cast(unsigned, pvv[1]) >> 16);
      pa[2] = (short)(ushort)(__builtin_bit_cast(unsigned, pvv[2]) >> 16);
      pa[3] = (short)(ushort)(__builtin_bit_cast(unsigned, pvv[3]) >> 16);

      const int kqoff = ((sub << 2) + g) << 7;  // kq*128 bytes
      __builtin_amdgcn_s_setprio(1);
#pragma unroll
      for (int dt = 0; dt < 16; ++dt) {
        s16x4_t vf = *(const s16x4_t*)(lv + (dt << 10) + kqoff + (lr << 3));
        oacc[dt] = mfma_pv(pa, vf, oacc[dt]);
      }
      __builtin_amdgcn_s_setprio(0);
    }
    __syncthreads();  // drains gloads (next tile ready) + all waves done with cur
    cur ^= 1;
  }

  l_r += __shfl_xor(l_r, 16);
  l_r += __shfl_xor(l_r, 32);
  float dn[4];
#pragma unroll
  for (int r = 0; r < 4; ++r)
    dn[r] = 1.0f / __shfl(l_r, (g << 2) + r);

  const int orow0 = b * NS + qb0 + (w << 4) + (g << 2);
#pragma unroll
  for (int dt = 0; dt < 16; ++dt) {
    int col = h * DH + (dt << 4) + lr;
#pragma unroll
    for (int r = 0; r < 4; ++r) {
      ao[(size_t)(orow0 + r) * (NHEADS * DH) + col] = f2bf(oacc[dt][r] * dn[r]);
    }
  }
}

extern "C" void kernel_launch(void* const* d_in, const int* in_sizes, int n_in,
                              void* d_out, int out_size, void* d_ws, size_t ws_size,
                              hipStream_t stream) {
  const float* hs   = (const float*)d_in[0];
  const float* sint = (const float*)d_in[3];
  const float* cost = (const float*)d_in[4];
  const float* Wq = (const float*)d_in[6];
  const float* Wk = (const float*)d_in[7];
  const float* Wv = (const float*)d_in[8];
  const float* Wo = (const float*)d_in[9];

  char* ws = (char*)d_ws;
  size_t off = 0;
  auto alloc = [&](size_t bytes) {
    char* p = ws + off;
    off += (bytes + 255) & ~(size_t)255;
    return p;
  };
  ushort* hsb   = (ushort*)alloc((size_t)4096 * 3584 * 2);  // hs in bf16
  ushort* wT    = (ushort*)alloc((size_t)4096 * 3584 * 2);  // reused weight^T buffer
  ushort* qbuf  = (ushort*)alloc((size_t)4096 * 4096 * 2);
  ushort* kbuf  = (ushort*)alloc((size_t)4096 * 2048 * 2);  // MUST precede vtbuf
  ushort* vtbuf = (ushort*)alloc((size_t)4096 * 2048 * 2);  // = kbuf + 4096*2048 (tiled)
  ushort* aobuf = qbuf;  // alias: attn writes exactly the region only it reads
  if (off > ws_size) return;

  // hs f32 -> bf16
  f32_to_bf16_kernel<<<(4096 * 3584 / 4) / 256, 256, 0, stream>>>(hs, hsb, 4096 * 3584 / 4);

  // fused K+V projection (RoPE fused on K half): Bt = [WkT; WvT] stacked in wT
  transpose_f32_bf16<<<(3584 / 64) * (2048 / 64), 256, 0, stream>>>(Wk, wT, 3584, 2048);
  transpose_f32_bf16<<<(3584 / 64) * (2048 / 64), 256, 0, stream>>>(Wv, wT + (size_t)2048 * 3584, 3584, 2048);
  gemm256<5><<<16 * 16, 512, 0, stream>>>(hsb, wT, kbuf, sint, cost, 4096, 4096, 3584);

  // Q projection (RoPE fused)
  transpose_f32_bf16<<<(3584 / 64) * (4096 / 64), 256, 0, stream>>>(Wq, wT, 3584, 4096);
  gemm256<1><<<16 * 16, 512, 0, stream>>>(hsb, wT, qbuf, sint, cost, 4096, 4096, 3584);

  // attention: QBLK=64, LPT/XCD decode (ao aliases qbuf)
  attn_kernel<<<NB * NHEADS * (NS / 64), 256, 0, stream>>>(qbuf, kbuf, vtbuf, aobuf);

  // output projection, f32 out
  transpose_f32_bf16<<<(4096 / 64) * (3584 / 64), 256, 0, stream>>>(Wo, wT, 4096, 3584);
  gemm256<2><<<16 * 14, 512, 0, stream>>>(aobuf, wT, d_out, nullptr, nullptr, 4096, 3584, 4096);
}

// Round 21
// 510.375 us; speedup vs baseline: 1.0916x; 1.0916x over previous
//
#include <hip/hip_runtime.h>
#include <hip/hip_bf16.h>

typedef __bf16 bf16x8_t __attribute__((ext_vector_type(8)));
typedef __bf16 bf16x4_t __attribute__((ext_vector_type(4)));
typedef short s16x4_t  __attribute__((ext_vector_type(4)));
typedef float f32x4_t  __attribute__((ext_vector_type(4)));

#define NB 2
#define NS 2048
#define NHID 3584
#define NHEADS 16
#define NKVH 8
#define DH 256
#define WIN 1024

__device__ __forceinline__ float bf2f(ushort u) {
  union { unsigned v; float f; } x; x.v = ((unsigned)u) << 16; return x.f;
}
__device__ __forceinline__ ushort f2bf(float f) {
  unsigned x = __builtin_bit_cast(unsigned, f);
  unsigned r = (x + 0x7fffu + ((x >> 16) & 1u)) >> 16;
  return (ushort)r;
}

__device__ __forceinline__ void gload16(const void* g, void* l) {
  __builtin_amdgcn_global_load_lds((const __attribute__((address_space(1))) void*)g,
                                   (__attribute__((address_space(3))) void*)l, 16, 0, 0);
}

__device__ __forceinline__ f32x4_t mfma_pv(s16x4_t a, s16x4_t b, f32x4_t c) {
#if __has_builtin(__builtin_amdgcn_mfma_f32_16x16x16_bf16)
  return __builtin_amdgcn_mfma_f32_16x16x16_bf16(
      __builtin_bit_cast(bf16x4_t, a), __builtin_bit_cast(bf16x4_t, b), c, 0, 0, 0);
#else
  return __builtin_amdgcn_mfma_f32_16x16x16bf16_1k(a, b, c, 0, 0, 0);
#endif
}

__device__ __forceinline__ float fexp2(float x) {
#if __has_builtin(__builtin_amdgcn_exp2f)
  return __builtin_amdgcn_exp2f(x);
#else
  return exp2f(x);
#endif
}
__device__ __forceinline__ float frcp(float x) {
#if __has_builtin(__builtin_amdgcn_rcpf)
  return __builtin_amdgcn_rcpf(x);
#else
  return 1.0f / x;
#endif
}

// softcap softmax weight, uniformly scaled by e^-25 (cancels in l-normalize):
// p' = exp(25 - 100/(e^{2x}+1)), x = s/800  ==> exp2 form, clamp-free
__device__ __forceinline__ float pexp(float s) {
  float e = fexp2(s * 0.0036067376f);
  float r = frcp(e + 1.0f);
  return fexp2(36.067376f - 144.2695041f * r);
}

// ---------------- f32 -> bf16 elementwise convert (x4 vectorized) ---------
__global__ __launch_bounds__(256) void f32_to_bf16_kernel(const float* __restrict__ in,
                                                          ushort* __restrict__ out, int n4) {
  int i = (int)blockIdx.x * 256 + (int)threadIdx.x;
  if (i < n4) {
    float4 v = ((const float4*)in)[i];
    ushort4 o;
    o.x = f2bf(v.x); o.y = f2bf(v.y); o.z = f2bf(v.z); o.w = f2bf(v.w);
    ((ushort4*)out)[i] = o;
  }
}

// ------------- transpose+convert: f32 in[R][C] -> bf16 out[C][R] ----------
// Vectorized: float4 global loads (1KB/wave), ushort4 LDS writes,
// uint4 global stores (8 contiguous out-elements per thread-iter).
__global__ __launch_bounds__(256) void transpose_f32_bf16(const float* __restrict__ in,
                                                          ushort* __restrict__ out,
                                                          int R, int Cc) {
  __shared__ ushort tile[64][72];
  const int t = threadIdx.x;
  const int ct = Cc >> 6;
  const int by = blockIdx.x / ct;
  const int bx = blockIdx.x % ct;
  const int r0 = by << 6, c0 = bx << 6;
#pragma unroll
  for (int i = 0; i < 4; ++i) {
    int v = i * 256 + t;            // 0..1023
    int r = v >> 4, c4 = (v & 15) << 2;
    float4 f = *(const float4*)(in + (size_t)(r0 + r) * Cc + c0 + c4);
    ushort4 o;
    o.x = f2bf(f.x); o.y = f2bf(f.y); o.z = f2bf(f.z); o.w = f2bf(f.w);
    *(ushort4*)&tile[r][c4] = o;    // 144B row stride -> 8B aligned
  }
  __syncthreads();
#pragma unroll
  for (int i = 0; i < 2; ++i) {
    int v = i * 256 + t;            // 0..511
    int rr = v >> 3;                // out-row (= in-col) 0..63
    int c8 = (v & 7) << 3;          // chunk of 8 in-rows
    ushort o[8];
#pragma unroll
    for (int e = 0; e < 8; ++e) o[e] = tile[c8 + e][rr];
    *(uint4*)(out + (size_t)(c0 + rr) * R + r0 + c8) = *(const uint4*)o;
  }
}

// ============ 256x256 GEMM, single-barrier K-loop (round-19 best) =========
// Stages write buf^1 while ds_reads target buf (disjoint); every ds_read dest
// is consumed by MFMA before TBAR, so lgkm retired block-wide at the single
// vmcnt(0)+s_barrier per K-tile. Fragment prefetch rotation gives each MFMA a
// full phase of ds-read slack via compiler-counted lgkm waits.
#define TBAR do { \
    asm volatile("s_waitcnt vmcnt(0)" ::: "memory"); \
    __builtin_amdgcn_sched_barrier(0); \
    __builtin_amdgcn_s_barrier(); } while (0)

// EPI=1: bf16 C[M][N] + fused RoPE. EPI=2: f32 C. EPI=5: fused KV — K half
// WITH RoPE -> kbuf; V half -> vtbuf ATTN-TILED: elem(b,kvh,s,d) =
//   plane*524288 + (s>>5)*8192 + (d>>4)*512 + ((s&31)>>2)*64 + (d&15)*4 + (s&3)
template <int EPI>
__global__ __launch_bounds__(512, 2) void gemm256(const ushort* __restrict__ A,
                                                  const ushort* __restrict__ Bt,
                                                  void* __restrict__ Cout,
                                                  const float* __restrict__ sinT,
                                                  const float* __restrict__ cosT,
                                                  int M, int N, int K) {
  __shared__ alignas(16) char lds[131072];
  const int t = threadIdx.x;
  const int lane = t & 63;
  const int wid = t >> 6;
  const int wm = wid >> 2;   // 0..1
  const int wn = wid & 3;    // 0..3
  const int g = lane >> 4;
  const int lr = lane & 15;
  const int lrow8 = lane >> 3;
  const int lp = (lane & 7) ^ lrow8;  // pre-swizzled staging chunk

  const int nbn = N >> 8;
  const int nwg = (int)gridDim.x;
  const int bid = (int)blockIdx.x;
  const int swz = (bid & 7) * (nwg >> 3) + (bid >> 3);
  const int bm = swz / nbn, bn = swz % nbn;
  const int m0 = bm << 8, n0 = bn << 8;

  f32x4_t acc[8][4] = {};
  const int T = K >> 6;

  auto stageA = [&](int q, int koff, int bufn) {
    int row = (q << 6) + (wid << 3) + lrow8;
    gload16(A + (size_t)(m0 + row) * K + koff + (lp << 3),
            lds + bufn * 32768 + (q << 13) + (wid << 10));
  };
  auto stageB = [&](int q, int koff, int bufn) {
    int row = (q << 6) + (wid << 3) + lrow8;
    gload16(Bt + (size_t)(n0 + row) * K + koff + (lp << 3),
            lds + 65536 + bufn * 32768 + (q << 13) + (wid << 10));
  };
  auto ldAfrag = [&](bf16x8_t* dst, const char* cA, int mh, int ks) {
#pragma unroll
    for (int i = 0; i < 4; ++i) {
      int row = (wm << 7) + (mh << 6) + (i << 4) + lr;
      dst[i] = *(const bf16x8_t*)(cA + (row << 7) + (((ks << 6) + (g << 4)) ^ ((row & 7) << 4)));
    }
  };
  auto ldBfrag = [&](bf16x8_t* dst, const char* cB, int ks) {
#pragma unroll
    for (int j = 0; j < 4; ++j) {
      int row = (wn << 6) + (j << 4) + lr;
      dst[j] = *(const bf16x8_t*)(cB + (row << 7) + (((ks << 6) + (g << 4)) ^ ((row & 7) << 4)));
    }
  };

  // prologue: tile 0 -> buf 0
#pragma unroll
  for (int q = 0; q < 4; ++q) { stageA(q, 0, 0); stageB(q, 0, 0); }
  asm volatile("s_waitcnt vmcnt(0)" ::: "memory");
  __builtin_amdgcn_s_barrier();

  bf16x8_t afA[4], afB[4], bfvA[4], bfvB[4];
  ldAfrag(afA, lds, 0, 0);
  ldBfrag(bfvA, lds + 65536, 0);

  for (int tt = 0; tt < T; ++tt) {
    const int bc = tt & 1;
    const int bnx = bc ^ 1;
    const bool st = (tt + 1 < T);
    const int kn = (tt + 1) << 6;
    const char* cA = lds + bc * 32768;
    const char* cB = lds + 65536 + bc * 32768;

    // ---- phase 0: MFMA(afA,bfvA); prefetch afB=(mh1,ks0); stage A x4 ----
    ldAfrag(afB, cA, 1, 0);
    if (st) { stageA(0, kn, bnx); stageA(1, kn, bnx); stageA(2, kn, bnx); stageA(3, kn, bnx); }
    __builtin_amdgcn_s_setprio(1);
#pragma unroll
    for (int i = 0; i < 4; ++i)
#pragma unroll
      for (int j = 0; j < 4; ++j)
        acc[i][j] = __builtin_amdgcn_mfma_f32_16x16x32_bf16(afA[i], bfvA[j], acc[i][j], 0, 0, 0);
    __builtin_amdgcn_s_setprio(0);

    // ---- phase 1: MFMA(afB,bfvA); prefetch afA=(mh0,ks1), bfvB=(ks1); stage B x4 ----
    ldAfrag(afA, cA, 0, 1);
    ldBfrag(bfvB, cB, 1);
    if (st) { stageB(0, kn, bnx); stageB(1, kn, bnx); stageB(2, kn, bnx); stageB(3, kn, bnx); }
    __builtin_amdgcn_s_setprio(1);
#pragma unroll
    for (int i = 0; i < 4; ++i)
#pragma unroll
      for (int j = 0; j < 4; ++j)
        acc[4 + i][j] = __builtin_amdgcn_mfma_f32_16x16x32_bf16(afB[i], bfvA[j], acc[4 + i][j], 0, 0, 0);
    __builtin_amdgcn_s_setprio(0);

    // ---- phase 2: MFMA(afA,bfvB); prefetch afB=(mh1,ks1) ----
    ldAfrag(afB, cA, 1, 1);
    __builtin_amdgcn_s_setprio(1);
#pragma unroll
    for (int i = 0; i < 4; ++i)
#pragma unroll
      for (int j = 0; j < 4; ++j)
        acc[i][j] = __builtin_amdgcn_mfma_f32_16x16x32_bf16(afA[i], bfvB[j], acc[i][j], 0, 0, 0);
    __builtin_amdgcn_s_setprio(0);

    // ---- phase 3: MFMA(afB,bfvB); single per-tile drain + barrier ----
    __builtin_amdgcn_s_setprio(1);
#pragma unroll
    for (int i = 0; i < 4; ++i)
#pragma unroll
      for (int j = 0; j < 4; ++j)
        acc[4 + i][j] = __builtin_amdgcn_mfma_f32_16x16x32_bf16(afB[i], bfvB[j], acc[4 + i][j], 0, 0, 0);
    __builtin_amdgcn_s_setprio(0);
    TBAR;
    if (st) {  // first fragments of next tile from the freshly-drained buffer
      ldAfrag(afA, lds + bnx * 32768, 0, 0);
      ldBfrag(bfvA, lds + 65536 + bnx * 32768, 0);
    }
  }

  // ---- epilogue: stage tile in LDS, then wide (rope-fused) stores ----
  __syncthreads();
  const bool trstage = (EPI == 5) && (n0 >= 2048);
  if (trstage) {
#pragma unroll
    for (int i = 0; i < 8; ++i)
#pragma unroll
      for (int j = 0; j < 4; ++j) {
        int col = (wn << 6) + (j << 4) + lr;
#pragma unroll
        for (int r = 0; r < 4; ++r) {
          int row = (wm << 7) + (i << 4) + (g << 2) + r;
          *(ushort*)(lds + (col << 9) + ((row << 1) ^ ((col & 7) << 4))) = f2bf(acc[i][j][r]);
        }
      }
  } else {
#pragma unroll
    for (int i = 0; i < 8; ++i)
#pragma unroll
      for (int j = 0; j < 4; ++j) {
        int col = (wn << 6) + (j << 4) + lr;
#pragma unroll
        for (int r = 0; r < 4; ++r) {
          int row = (wm << 7) + (i << 4) + (g << 2) + r;
          *(ushort*)(lds + (row << 9) + ((col << 1) ^ ((row & 7) << 4))) = f2bf(acc[i][j][r]);
        }
      }
  }
  __syncthreads();

  if (EPI == 1) {
    ushort* C = (ushort*)Cout;
#pragma unroll
    for (int it = 0; it < 16; ++it) {
      int idx = it * 512 + t;
      int row = idx >> 5, ch = idx & 31;
      uint4 v = *(const uint4*)(lds + (row << 9) + ((ch << 4) ^ ((row & 7) << 4)));
      uint4 p = *(const uint4*)(lds + (row << 9) + (((ch ^ 16) << 4) ^ ((row & 7) << 4)));
      int pos = (m0 + row) & (NS - 1);
      int d0 = ch << 3;
      float4 c0 = *(const float4*)(cosT + (size_t)pos * 256 + d0);
      float4 c1 = *(const float4*)(cosT + (size_t)pos * 256 + d0 + 4);
      float4 s0 = *(const float4*)(sinT + (size_t)pos * 256 + d0);
      float4 s1 = *(const float4*)(sinT + (size_t)pos * 256 + d0 + 4);
      float cs[8] = {c0.x, c0.y, c0.z, c0.w, c1.x, c1.y, c1.z, c1.w};
      float ss[8] = {s0.x, s0.y, s0.z, s0.w, s1.x, s1.y, s1.z, s1.w};
      const float sgn = (ch < 16) ? -1.f : 1.f;
      const ushort* vv = (const ushort*)&v;
      const ushort* pp = (const ushort*)&p;
      ushort o[8];
#pragma unroll
      for (int e = 0; e < 8; ++e)
        o[e] = f2bf(bf2f(vv[e]) * cs[e] + sgn * bf2f(pp[e]) * ss[e]);
      *(uint4*)(C + (size_t)(m0 + row) * N + n0 + (ch << 3)) = *(const uint4*)o;
    }
  } else if (EPI == 5) {
    ushort* C = (ushort*)Cout;
    if (n0 < 2048) {  // K half -> kbuf, WITH RoPE
#pragma unroll
      for (int it = 0; it < 16; ++it) {
        int idx = it * 512 + t;
        int row = idx >> 5, ch = idx & 31;
        uint4 v = *(const uint4*)(lds + (row << 9) + ((ch << 4) ^ ((row & 7) << 4)));
        uint4 p = *(const uint4*)(lds + (row << 9) + (((ch ^ 16) << 4) ^ ((row & 7) << 4)));
        int pos = (m0 + row) & (NS - 1);
        int d0 = ch << 3;
        float4 c0 = *(const float4*)(cosT + (size_t)pos * 256 + d0);
        float4 c1 = *(const float4*)(cosT + (size_t)pos * 256 + d0 + 4);
        float4 s0 = *(const float4*)(sinT + (size_t)pos * 256 + d0);
        float4 s1 = *(const float4*)(sinT + (size_t)pos * 256 + d0 + 4);
        float cs[8] = {c0.x, c0.y, c0.z, c0.w, c1.x, c1.y, c1.z, c1.w};
        float ss[8] = {s0.x, s0.y, s0.z, s0.w, s1.x, s1.y, s1.z, s1.w};
        const float sgn = (ch < 16) ? -1.f : 1.f;
        const ushort* vv = (const ushort*)&v;
        const ushort* pp = (const ushort*)&p;
        ushort o[8];
#pragma unroll
        for (int e = 0; e < 8; ++e)
          o[e] = f2bf(bf2f(vv[e]) * cs[e] + sgn * bf2f(pp[e]) * ss[e]);
        *(uint4*)(C + (size_t)(m0 + row) * 2048 + n0 + (ch << 3)) = *(const uint4*)o;
      }
    } else {
      // V half -> tiled vtbuf (no rope). Fully linear store: elem = base + s*8.
      ushort* vC = C + (size_t)4096 * 2048;
      const int plane = (m0 >> 11) * NKVH + ((n0 - 2048) >> 8);
      ushort* dst = vC + (size_t)plane * ((size_t)NS * DH) + (size_t)((m0 & (NS - 1)) >> 5) * 8192;
#pragma unroll
      for (int it = 0; it < 16; ++it) {
        int s = it * 512 + t;
        int lr2 = s & 7, kq = (s >> 3) & 7, dt_l = (s >> 6) & 15, sb_l = s >> 10;
        int d0 = (dt_l << 4) + (lr2 << 1);   // lds col
        int r0 = (sb_l << 5) + (kq << 2);    // lds row (token)
        uint2 a = *(const uint2*)(lds + (d0 << 9) + ((r0 << 1) ^ ((d0 & 7) << 4)));
        uint2 b2 = *(const uint2*)(lds + ((d0 + 1) << 9) + ((r0 << 1) ^ (((d0 + 1) & 7) << 4)));
        uint4 v; v.x = a.x; v.y = a.y; v.z = b2.x; v.w = b2.y;
        *(uint4*)(dst + (size_t)s * 8) = v;
      }
    }
  } else {
    float* Cf = (float*)Cout;
#pragma unroll
    for (int it = 0; it < 32; ++it) {
      int idx = it * 512 + t;
      int row = idx >> 6, qd = idx & 63;
      ushort4 hv = *(const ushort4*)(lds + (row << 9) + ((qd << 3) ^ ((row & 7) << 4)));
      float4 fv;
      fv.x = bf2f(hv.x); fv.y = bf2f(hv.y); fv.z = bf2f(hv.z); fv.w = bf2f(hv.w);
      *(float4*)(Cf + (size_t)(m0 + row) * N + n0 + (qd << 2)) = fv;
    }
  }
}

// ---------------- flash attention v6.1 (best measured: 147us) --------------
// grid 1024. xcd=bid&7 -> planes {2x,2x+1}; heavy q-blocks first (LPT).
// Tiled-V (linear gload16, bank-bijective PV reads). exp2 softcap softmax.
__global__ __launch_bounds__(256) void attn_kernel(const ushort* __restrict__ q,
                                                   const ushort* __restrict__ k,
                                                   const ushort* __restrict__ vt,
                                                   ushort* __restrict__ ao) {
  __shared__ alignas(16) char lK[2][16384];
  __shared__ alignas(16) char lV[2][16384];
  const int bid = (int)blockIdx.x;
  const int x = bid & 7;
  const int s_ = bid >> 3;       // 0..127
  const int rnd = s_ >> 5;       // 0..3
  const int c = s_ & 31;
  const int a = c >> 1;
  const int hl = c & 1;
  const int plane = (x << 1) | (rnd & 1);
  int qb;
  if (rnd < 2) qb = 16 + a;          // heavy first (LPT)
  else if (rnd == 2) qb = a;         // light ascending
  else qb = 15 - a;                  // light descending
  const int b = plane >> 3;
  const int kvh = plane & 7;
  const int h = (kvh << 1) | hl;
  const int qb0 = qb << 6;
  const int t = threadIdx.x;
  const int lane = t & 63;
  const int w = t >> 6;
  const int g = lane >> 4;
  const int lr = lane & 15;

  const int qrow = qb0 + (w << 4) + lr;
  bf16x8_t qf[8];
  const ushort* qbase = q + (size_t)(b * NS + qrow) * (NHEADS * DH) + h * DH;
#pragma unroll
  for (int ks = 0; ks < 8; ++ks)
    qf[ks] = *(const bf16x8_t*)(qbase + (ks << 5) + (g << 3));

  float l_r = 0.f;
  f32x4_t oacc[16] = {};

  const int qminw = qb0 + (w << 4);
  const int qmaxw = qminw + 15;
  int t_lo = qb0 - (WIN - 1);
  if (t_lo < 0) t_lo = 0;
  t_lo &= ~31;
  const int t_hi = qb0 + 63;
  const int nt = ((t_hi - t_lo) >> 5) + 1;

  const ushort* kgb = k + (size_t)(b * NS) * (NKVH * DH) + kvh * DH;
  const ushort* vgb = vt + (size_t)(b * NKVH + kvh) * ((size_t)NS * DH);  // tiled plane

  auto stage = [&](int kt, int bi) {
    char* dk = lK[bi];
    char* dv = lV[bi];
    const int sb = kt >> 5;
#pragma unroll
    for (int j = 0; j < 4; ++j) {
      int i = (w << 2) + j;  // 0..15
      int row = (i << 1) + (lane >> 5);
      int ck = (lane & 31) ^ (row & 7);
      gload16(kgb + (size_t)(kt + row) * (NKVH * DH) + (ck << 3), dk + (i << 10));
      gload16(vgb + (size_t)sb * 8192 + (((i << 6) + lane) << 3), dv + (i << 10));
    }
  };

  int cur = 0;
  stage(t_lo, 0);
  __syncthreads();

  for (int i = 0; i < nt; ++i) {
    const int kt = t_lo + (i << 5);
    if (i + 1 < nt) stage(kt + 32, cur ^ 1);  // async prefetch into other buf
    const char* lk = lK[cur];
    const char* lv = lV[cur];
#pragma unroll
    for (int sub = 0; sub < 2; ++sub) {
      const int key0 = kt + (sub << 4);
      if (key0 > qmaxw) continue;
      if (key0 + 15 < qminw - (WIN - 1)) continue;

      f32x4_t sacc = {};
      __builtin_amdgcn_s_setprio(1);
#pragma unroll
      for (int ks = 0; ks < 8; ++ks) {
        int row = (sub << 4) + lr;
        bf16x8_t kf = *(const bf16x8_t*)(lk + (((row << 9) + (ks << 6) + (g << 4)) ^ ((row & 7) << 4)));
        sacc = __builtin_amdgcn_mfma_f32_16x16x32_bf16(kf, qf[ks], sacc, 0, 0, 0);
      }
      __builtin_amdgcn_s_setprio(0);

      float pvv[4];
      const bool full = (key0 + 15 <= qminw) && (key0 >= qmaxw - (WIN - 1));
      if (full) {
#pragma unroll
        for (int r = 0; r < 4; ++r) { pvv[r] = pexp(sacc[r]); l_r += pvv[r]; }
      } else {
#pragma unroll
        for (int r = 0; r < 4; ++r) {
          int key = key0 + (g << 2) + r;
          bool ok = (key <= qrow) && (qrow - key < WIN);
          pvv[r] = ok ? pexp(sacc[r]) : 0.f;
          l_r += pvv[r];
        }
      }

      s16x4_t pa;  // truncating f32->bf16 (bias <=0.4%, inside threshold)
      pa[0] = (short)(ushort)(__builtin_bit_cast(unsigned, pvv[0]) >> 16);
      pa[1] = (short)(ushort)(__builtin_bit_cast(unsigned, pvv[1]) >> 16);
      pa[2] = (short)(ushort)(__builtin_bit_cast(unsigned, pvv[2]) >> 16);
      pa[3] = (short)(ushort)(__builtin_bit_cast(unsigned, pvv[3]) >> 16);

      const int kqoff = ((sub << 2) + g) << 7;  // kq*128 bytes
      __builtin_amdgcn_s_setprio(1);
#pragma unroll
      for (int dt = 0; dt < 16; ++dt) {
        s16x4_t vf = *(const s16x4_t*)(lv + (dt << 10) + kqoff + (lr << 3));
        oacc[dt] = mfma_pv(pa, vf, oacc[dt]);
      }
      __builtin_amdgcn_s_setprio(0);
    }
    __syncthreads();  // drains gloads (next tile ready) + all waves done with cur
    cur ^= 1;
  }

  l_r += __shfl_xor(l_r, 16);
  l_r += __shfl_xor(l_r, 32);
  float dn[4];
#pragma unroll
  for (int r = 0; r < 4; ++r)
    dn[r] = 1.0f / __shfl(l_r, (g << 2) + r);

  const int orow0 = b * NS + qb0 + (w << 4) + (g << 2);
#pragma unroll
  for (int dt = 0; dt < 16; ++dt) {
    int col = h * DH + (dt << 4) + lr;
#pragma unroll
    for (int r = 0; r < 4; ++r) {
      ao[(size_t)(orow0 + r) * (NHEADS * DH) + col] = f2bf(oacc[dt][r] * dn[r]);
    }
  }
}

extern "C" void kernel_launch(void* const* d_in, const int* in_sizes, int n_in,
                              void* d_out, int out_size, void* d_ws, size_t ws_size,
                              hipStream_t stream) {
  const float* hs   = (const float*)d_in[0];
  const float* sint = (const float*)d_in[3];
  const float* cost = (const float*)d_in[4];
  const float* Wq = (const float*)d_in[6];
  const float* Wk = (const float*)d_in[7];
  const float* Wv = (const float*)d_in[8];
  const float* Wo = (const float*)d_in[9];

  char* ws = (char*)d_ws;
  size_t off = 0;
  auto alloc = [&](size_t bytes) {
    char* p = ws + off;
    off += (bytes + 255) & ~(size_t)255;
    return p;
  };
  ushort* hsb   = (ushort*)alloc((size_t)4096 * 3584 * 2);  // hs in bf16
  ushort* wT    = (ushort*)alloc((size_t)4096 * 3584 * 2);  // reused weight^T buffer
  ushort* qbuf  = (ushort*)alloc((size_t)4096 * 4096 * 2);
  ushort* kbuf  = (ushort*)alloc((size_t)4096 * 2048 * 2);  // MUST precede vtbuf
  ushort* vtbuf = (ushort*)alloc((size_t)4096 * 2048 * 2);  // = kbuf + 4096*2048 (tiled)
  ushort* aobuf = qbuf;  // alias: attn writes exactly the region only it reads
  if (off > ws_size) return;

  // hs f32 -> bf16
  f32_to_bf16_kernel<<<(4096 * 3584 / 4) / 256, 256, 0, stream>>>(hs, hsb, 4096 * 3584 / 4);

  // fused K+V projection (RoPE fused on K half): Bt = [WkT; WvT] stacked in wT
  transpose_f32_bf16<<<(3584 / 64) * (2048 / 64), 256, 0, stream>>>(Wk, wT, 3584, 2048);
  transpose_f32_bf16<<<(3584 / 64) * (2048 / 64), 256, 0, stream>>>(Wv, wT + (size_t)2048 * 3584, 3584, 2048);
  gemm256<5><<<16 * 16, 512, 0, stream>>>(hsb, wT, kbuf, sint, cost, 4096, 4096, 3584);

  // Q projection (RoPE fused)
  transpose_f32_bf16<<<(3584 / 64) * (4096 / 64), 256, 0, stream>>>(Wq, wT, 3584, 4096);
  gemm256<1><<<16 * 16, 512, 0, stream>>>(hsb, wT, qbuf, sint, cost, 4096, 4096, 3584);

  // attention: QBLK=64, LPT/XCD decode (ao aliases qbuf)
  attn_kernel<<<NB * NHEADS * (NS / 64), 256, 0, stream>>>(qbuf, kbuf, vtbuf, aobuf);

  // output projection, f32 out
  transpose_f32_bf16<<<(4096 / 64) * (3584 / 64), 256, 0, stream>>>(Wo, wT, 4096, 3584);
  gemm256<2><<<16 * 14, 512, 0, stream>>>(aobuf, wT, d_out, nullptr, nullptr, 4096, 3584, 4096);
}